// Round 16
// baseline (670.476 us; speedup 1.0000x reference)
//
#include <hip/hip_runtime.h>
#include <math.h>

// Swin block: B=8 H=W=128 C=256 NH=8 HD=32 WS=8 SS=4, N=64 tokens/window,
// 2048 windows, 131072 tokens.

#define NWIN_TOTAL 2048
#define TOK_TOTAL  131072
#define SCALE_Q    0.17677669529663687f  // 32^-0.5
#define LOG2E      1.4426950408889634f

typedef unsigned short u16;
typedef __attribute__((ext_vector_type(4))) unsigned short u16x4;
typedef __attribute__((ext_vector_type(8))) unsigned short u16x8;
typedef __attribute__((ext_vector_type(8))) short bf16x8;   // MFMA A/B frag (4 VGPR)
typedef __attribute__((ext_vector_type(4))) float f32x4;    // MFMA C/D frag

#define AS1 __attribute__((address_space(1)))
#define AS3 __attribute__((address_space(3)))
#define GLOAD_LDS16(g, l) \
  __builtin_amdgcn_global_load_lds((const AS1 unsigned int*)(g), (AS3 unsigned int*)(l), 16, 0, 0)

__device__ __forceinline__ float bf2f(u16 u) {
  union { unsigned int i; float f; } c; c.i = ((unsigned int)u) << 16; return c.f;
}
__device__ __forceinline__ u16 f2bf(float f) {
  union { float f; unsigned int i; } c; c.f = f;
  return (u16)((c.i + 0x7fff + ((c.i >> 16) & 1)) >> 16);
}
__device__ __forceinline__ int regid3(int h) { return h < 120 ? 0 : (h < 124 ? 1 : 2); }
// tanh-form GELU: v*t/(t+1), t = exp2(v*(2*log2e*sqrt(2/pi))*(1+0.044715 v^2))
__device__ __forceinline__ float gelu_f(float v) {
  float t = exp2f(v * fmaf(v * v, 0.10294423f, 2.3022082f));
  return v * t * __builtin_amdgcn_rcpf(t + 1.0f);
}

// (window g, token n) -> flat token index in image space (shift applied)
__device__ __forceinline__ int win_tok_to_t(int g, int n) {
  int b = g >> 8, wi = g & 255;
  int wr = wi >> 4, wc = wi & 15;
  int hs = wr * 8 + (n >> 3), ws2 = wc * 8 + (n & 7);
  int h = (hs + 4) & 127, w = (ws2 + 4) & 127;
  return (b << 14) + (h << 7) + w;
}

// ---------------- weight convert + transpose: [K][N] f32 -> [N][K] bf16 ----------------
__global__ __launch_bounds__(256)
void wconv_kernel(const float* __restrict__ w, u16* __restrict__ wt, int K, int N)
{
  int i = blockIdx.x * 256 + threadIdx.x;
  if (i >= K * N) return;
  int k = i / N, n = i - k * N;
  wt[(size_t)n * K + k] = f2bf(w[i]);
}

// ---------------- fused LN1 + qkv GEMM: one block per window, 16 waves ----------------
__global__ __launch_bounds__(1024)
void qln_kernel(const float* __restrict__ x, const float* __restrict__ g1,
                const float* __restrict__ b1, const u16* __restrict__ qkvT,
                const float* __restrict__ qkv_b,
                u16* __restrict__ qb, u16* __restrict__ kb, u16* __restrict__ vb,
                int g0)
{
  __shared__ u16 Aln[16384];   // [64 tok][256 k] bf16, 16B-gran ^= tok&7 (32 KB)
  const int tid = threadIdx.x, wid = tid >> 6, lane = tid & 63;
  const int l15 = lane & 15, g = lane >> 4;
  const int bwi = blockIdx.x;
  const int gw = g0 + bwi;

  // ---- LN1 stage with shifted-window gather: 16 lanes per row, 16 cols each ----
  {
    const int row = tid >> 4;
    const int cq = (tid & 15) * 16;
    const int t = win_tok_to_t(gw, row);
    const float* src = x + (size_t)t * 256 + cq;
    float vals[16];
    float s = 0.f, q = 0.f;
#pragma unroll
    for (int i = 0; i < 4; ++i) {
      float4 v = ((const float4*)src)[i];
      vals[i*4] = v.x; vals[i*4+1] = v.y; vals[i*4+2] = v.z; vals[i*4+3] = v.w;
      s += v.x + v.y + v.z + v.w;
      q += v.x*v.x + v.y*v.y + v.z*v.z + v.w*v.w;
    }
    s += __shfl_xor(s, 1, 64); q += __shfl_xor(q, 1, 64);
    s += __shfl_xor(s, 2, 64); q += __shfl_xor(q, 2, 64);
    s += __shfl_xor(s, 4, 64); q += __shfl_xor(q, 4, 64);
    s += __shfl_xor(s, 8, 64); q += __shfl_xor(q, 8, 64);
    float mean = s * 0.00390625f;
    float rstd = rsqrtf(q * 0.00390625f - mean * mean + 1e-5f);
#pragma unroll
    for (int i = 0; i < 2; ++i) {
      const int col = cq + i * 8;
      u16x8 o;
#pragma unroll
      for (int j = 0; j < 8; ++j)
        o[j] = f2bf((vals[i*8+j] - mean) * rstd * g1[col+j] + b1[col+j]);
      const int gran = col >> 3;
      *(u16x8*)((char*)Aln + row * 512 + ((gran ^ (row & 7)) << 4)) = o;
    }
  }
  __syncthreads();

  // ---- GEMM: acc[m][n], row = tok (m*16+g*4+r), col = wid*48 + n*16 + l15 ----
  f32x4 acc[4][3];
#pragma unroll
  for (int m = 0; m < 4; ++m)
#pragma unroll
    for (int n = 0; n < 3; ++n) acc[m][n] = (f32x4){0.f, 0.f, 0.f, 0.f};
  const int colb = wid * 48;
#pragma unroll
  for (int ks = 0; ks < 8; ++ks) {
    bf16x8 af[4], bw[3];
#pragma unroll
    for (int m = 0; m < 4; ++m) {
      const int tok = m * 16 + l15;
      const int gran = ks * 4 + g;
      af[m] = *(const bf16x8*)&Aln[tok * 256 + ((gran ^ (tok & 7)) << 3)];
    }
#pragma unroll
    for (int n = 0; n < 3; ++n)
      bw[n] = *(const bf16x8*)(qkvT + (size_t)(colb + n * 16 + l15) * 256 + ks * 32 + g * 8);
#pragma unroll
    for (int m = 0; m < 4; ++m)
#pragma unroll
      for (int n = 0; n < 3; ++n)
        acc[m][n] = __builtin_amdgcn_mfma_f32_16x16x32_bf16(af[m], bw[n], acc[m][n], 0, 0, 0);
  }

  // ---- epilogue: +bias; q scaled token-major; k token-major; v transposed ----
#pragma unroll
  for (int n = 0; n < 3; ++n) {
    const int col16 = colb + n * 16;
    const float bv = qkv_b[col16 + l15];
    const int s = col16 >> 8, head = (col16 >> 5) & 7, hd = col16 & 31;
    if (s == 2) {
      const size_t obase = ((size_t)bwi << 14) + ((size_t)head << 11) + (size_t)(hd + l15) * 64;
#pragma unroll
      for (int m = 0; m < 4; ++m) {
        const int tok0 = m * 16 + g * 4;
        u16x4 pk;
#pragma unroll
        for (int r = 0; r < 4; ++r) pk[r] = f2bf(acc[m][n][r] + bv);
        *(u16x4*)&vb[obase + tok0] = pk;
      }
    } else {
      u16* qdst = (s == 0) ? qb : kb;
      const float scl = (s == 0) ? SCALE_Q * LOG2E : 1.f;
      const size_t obase = ((size_t)bwi << 14) + ((size_t)head << 11) + hd + l15;
#pragma unroll
      for (int m = 0; m < 4; ++m)
#pragma unroll
        for (int r = 0; r < 4; ++r) {
          const int tok = m * 16 + g * 4 + r;
          qdst[obase + ((size_t)tok << 5)] = f2bf((acc[m][n][r] + bv) * scl);
        }
    }
  }
}

// ---------------- fused attention + proj + shift-reverse + residual ----------------
// One block per window (8 waves = 8 heads), 512 threads.
__global__ __launch_bounds__(512)
void awp_kernel(const u16* __restrict__ qb, const u16* __restrict__ kb,
                const u16* __restrict__ vt, const float* __restrict__ rpb,
                const u16* __restrict__ pjT, const float* __restrict__ pjb,
                const float* __restrict__ x, float* __restrict__ out, int g0)
{
  __shared__ union {
    u16 pl[8][2048];     // per-wave P half-buffer [n 64][m 32] bf16, byte^=(n&3)<<4 (32 KB)
    u16 aoL[16384];      // [tok 64][ch 256] bf16, 16B-gran ^= tok&7 (32 KB)
    float rep[8192];     // [row 32][oc 256] f32, 16B-gran ^= row&3 (32 KB)
  } sb;
  __shared__ float rl[1800];   // rpb re-layout: [head][di+7][dj2+7], *LOG2E
  const int tid = threadIdx.x, hh = tid >> 6, lane = tid & 63;
  const int l15 = lane & 15, g = lane >> 4;
  const int bw = blockIdx.x;

  for (int i = tid; i < 1800; i += 512) {
    unsigned int h2 = (unsigned)i / 225u;
    unsigned int rem = (unsigned)i - h2 * 225u;
    unsigned int aa = rem / 15u, bb = rem - aa * 15u;
    rl[i] = rpb[(aa * 15u + 14u - bb) * 8u + h2] * LOG2E;
  }
  __syncthreads();

  const size_t base = ((size_t)(bw * 8 + hh)) << 11;

  // ---- S^T = K · Q^T ----
  bf16x8 qf[4], kf[4];
#pragma unroll
  for (int f = 0; f < 4; ++f) {
    qf[f] = *(const bf16x8*)(qb + base + (size_t)(f * 16 + l15) * 32 + g * 8);
    kf[f] = *(const bf16x8*)(kb + base + (size_t)(f * 16 + l15) * 32 + g * 8);
  }
  f32x4 acc[4][4];
#pragma unroll
  for (int mf = 0; mf < 4; ++mf)
#pragma unroll
    for (int nf = 0; nf < 4; ++nf) acc[mf][nf] = (f32x4){0.f, 0.f, 0.f, 0.f};
#pragma unroll
  for (int mf = 0; mf < 4; ++mf)
#pragma unroll
    for (int nf = 0; nf < 4; ++nf)
      acc[mf][nf] = __builtin_amdgcn_mfma_f32_16x16x32_bf16(kf[mf], qf[nf], acc[mf][nf], 0, 0, 0);

  // ---- bias + mask (log2 domain). m = mf*16 + g*4 + r ----
  const int gwin = g0 + bw;
  const int wrw = (gwin >> 4) & 15, wcw = gwin & 15;
  const bool edge = (wrw == 15) || (wcw == 15);
  const int i2b = g >> 1;
  const int j2b = (g & 1) * 4;
#pragma unroll
  for (int nf = 0; nf < 4; ++nf) {
    const int n = nf * 16 + l15;
    const int i1 = n >> 3, j1 = n & 7;
    const int rid1 = edge ? regid3(wrw * 8 + i1) * 3 + regid3(wcw * 8 + j1) : 0;
#pragma unroll
    for (int mf = 0; mf < 4; ++mf) {
      const int i2 = mf * 2 + i2b;
      const int ib = hh * 225 + (i1 - i2 + 7) * 15 + (j2b - j1 + 7);
      const int r2a = edge ? regid3(wrw * 8 + i2) * 3 : 0;
#pragma unroll
      for (int r = 0; r < 4; ++r) {
        float b = rl[ib + r];
        if (edge) {
          int rid2 = r2a + regid3(wcw * 8 + j2b + r);
          if (rid2 != rid1) b -= 144.2695f;
        }
        acc[mf][nf][r] += b;
      }
    }
  }

  // ---- softmax over m, per column n ----
  float inv[4];
#pragma unroll
  for (int nf = 0; nf < 4; ++nf) {
    float m0 = -1e30f;
#pragma unroll
    for (int mf = 0; mf < 4; ++mf)
#pragma unroll
      for (int r = 0; r < 4; ++r) m0 = fmaxf(m0, acc[mf][nf][r]);
    m0 = fmaxf(m0, __shfl_xor(m0, 16, 64));
    m0 = fmaxf(m0, __shfl_xor(m0, 32, 64));
    float s = 0.f;
#pragma unroll
    for (int mf = 0; mf < 4; ++mf)
#pragma unroll
      for (int r = 0; r < 4; ++r) {
        float p = exp2f(acc[mf][nf][r] - m0);
        acc[mf][nf][r] = p;
        s += p;
      }
    s += __shfl_xor(s, 16, 64);
    s += __shfl_xor(s, 32, 64);
    inv[nf] = 1.f / s;
  }

  // ---- O = P · V, P exchanged through per-wave half-buffer (m in 2 halves) ----
  bf16x8 vf[2][2];
#pragma unroll
  for (int df = 0; df < 2; ++df)
#pragma unroll
    for (int ks = 0; ks < 2; ++ks)
      vf[df][ks] = *(const bf16x8*)(vt + base + (size_t)(df * 16 + l15) * 64 + ks * 32 + g * 8);
  f32x4 accO[4][2];
#pragma unroll
  for (int nf = 0; nf < 4; ++nf)
#pragma unroll
    for (int df = 0; df < 2; ++df) accO[nf][df] = (f32x4){0.f, 0.f, 0.f, 0.f};
  char* plw = (char*)sb.pl[hh];
#pragma unroll
  for (int ks = 0; ks < 2; ++ks) {
#pragma unroll
    for (int nf = 0; nf < 4; ++nf) {
      const int n = nf * 16 + l15;
      const int swz = (n & 3) << 4;
#pragma unroll
      for (int mm = 0; mm < 2; ++mm) {
        const int mf = ks * 2 + mm;
        float p0 = acc[mf][nf][0] * inv[nf], p1 = acc[mf][nf][1] * inv[nf];
        float p2 = acc[mf][nf][2] * inv[nf], p3 = acc[mf][nf][3] * inv[nf];
        unsigned int pa, pb;
        asm("v_cvt_pk_bf16_f32 %0, %1, %2" : "=v"(pa) : "v"(p0), "v"(p1));
        asm("v_cvt_pk_bf16_f32 %0, %1, %2" : "=v"(pb) : "v"(p2), "v"(p3));
        uint2 w; w.x = pa; w.y = pb;
        *(uint2*)(plw + ((n * 64 + mm * 32 + g * 8) ^ swz)) = w;
      }
    }
#pragma unroll
    for (int nf = 0; nf < 4; ++nf) {
      const int n = nf * 16 + l15;
      const int swz = (n & 3) << 4;
      bf16x8 pf = *(const bf16x8*)(plw + ((n * 64 + g * 16) ^ swz));
#pragma unroll
      for (int df = 0; df < 2; ++df)
        accO[nf][df] = __builtin_amdgcn_mfma_f32_16x16x32_bf16(pf, vf[df][ks], accO[nf][df], 0, 0, 0);
    }
  }

  // ---- pack O into aoL[tok][ch] (aliases pl; all PV reads done first) ----
  __syncthreads();
#pragma unroll
  for (int nf = 0; nf < 4; ++nf)
#pragma unroll
    for (int r = 0; r < 4; ++r) {
      const int tok = nf * 16 + g * 4 + r;
#pragma unroll
      for (int df = 0; df < 2; ++df) {
        const int ch = hh * 32 + df * 16 + l15;
        *(u16*)((char*)sb.aoL + tok * 512 + ((((ch >> 3) ^ (tok & 7))) << 4) + (ch & 7) * 2) =
            f2bf(accO[nf][df][r]);
      }
    }
  __syncthreads();

  // ---- proj GEMM: wave hh owns oc slice [hh*32, +32); K = 256 ----
  f32x4 pacc[4][2];
#pragma unroll
  for (int mf = 0; mf < 4; ++mf)
#pragma unroll
    for (int of = 0; of < 2; ++of) pacc[mf][of] = (f32x4){0.f, 0.f, 0.f, 0.f};
  const u16* pB = pjT + (size_t)(hh * 32) * 256;
#pragma unroll
  for (int ks = 0; ks < 8; ++ks) {
    bf16x8 af[4], bwf[2];
#pragma unroll
    for (int mf = 0; mf < 4; ++mf) {
      const int tok = mf * 16 + l15;
      af[mf] = *(const bf16x8*)((char*)sb.aoL + tok * 512 + (((ks * 4 + g) ^ (tok & 7)) << 4));
    }
#pragma unroll
    for (int of = 0; of < 2; ++of)
      bwf[of] = *(const bf16x8*)(pB + (size_t)(of * 16 + l15) * 256 + ks * 32 + g * 8);
#pragma unroll
    for (int mf = 0; mf < 4; ++mf)
#pragma unroll
      for (int of = 0; of < 2; ++of)
        pacc[mf][of] = __builtin_amdgcn_mfma_f32_16x16x32_bf16(af[mf], bwf[of], pacc[mf][of], 0, 0, 0);
  }

  // ---- epilogue: two 32-row halves through rep; coalesced x+residual scatter ----
#pragma unroll
  for (int hp = 0; hp < 2; ++hp) {
    __syncthreads();
#pragma unroll
    for (int mm = 0; mm < 2; ++mm) {
      const int mf = hp * 2 + mm;
#pragma unroll
      for (int of = 0; of < 2; ++of) {
        const int oc = hh * 32 + of * 16 + l15;
        const float bv = pjb[oc];
#pragma unroll
        for (int r = 0; r < 4; ++r) {
          const int row = mm * 16 + g * 4 + r;
          *(float*)((char*)sb.rep + ((row * 1024 + oc * 4) ^ ((row & 3) << 4))) =
              pacc[mf][of][r] + bv;
        }
      }
    }
    __syncthreads();
    const int rowl = tid >> 4, coll = (tid & 15) * 16;
    const int tok = hp * 32 + rowl;
    const int t = win_tok_to_t(g0 + bw, tok);
    const float* xs = x + (size_t)t * 256 + coll;
    float* od = out + (size_t)t * 256 + coll;
#pragma unroll
    for (int i = 0; i < 4; ++i) {
      float4 rv = *(const float4*)((char*)sb.rep +
                    ((rowl * 1024 + (coll + i * 4) * 4) ^ ((rowl & 3) << 4)));
      float4 xv = ((const float4*)xs)[i];
      ((float4*)od)[i] = make_float4(rv.x + xv.x, rv.y + xv.y, rv.z + xv.z, rv.w + xv.w);
    }
  }
}

// ---------------- fused MLP v8: v6 8-wave split + single barrier/chunk (dbuf Hs) ----------------
// 64 tokens/block, 8 waves (512 thr), 64 KB LDS (same 2-block slot as 48 KB).
// Per chunk: { GEMM2(c-1) || GEMM1(c) -> GELU+pack->Hs[c&1] -> BAR }  (9 barriers total).
__global__ __launch_bounds__(512)
void mlp_kernel(float* io, const u16* __restrict__ w1t, const u16* __restrict__ w2t,
                const float* __restrict__ fb1, const float* __restrict__ fb2,
                const float* __restrict__ g2, const float* __restrict__ bt2)
{
  __shared__ u16 Aln[16384];    // [64 tok][256 k] bf16, 16B-gran ^= tok&7  (32 KB)
  __shared__ u16 Hs[2][8192];   // dbuf [64 tok][128 h] bf16, gran ^= tok&7 (32 KB)
  const int tid = threadIdx.x, wid = tid >> 6, lane = tid & 63;
  const int l15 = lane & 15, g = lane >> 4;
  const int t0 = blockIdx.x * 64;

  // ---- stage Aln with fused LN2 (8 lanes per row, 32 cols each) ----
  {
    const int row = tid >> 3;          // 0..63
    const int cq = (tid & 7) * 32;
    const float* src = io + (size_t)(t0 + row) * 256 + cq;
    float vals[32];
    float s = 0.f, q = 0.f;
#pragma unroll
    for (int i = 0; i < 8; ++i) {
      float4 v = ((const float4*)src)[i];
      vals[i*4] = v.x; vals[i*4+1] = v.y; vals[i*4+2] = v.z; vals[i*4+3] = v.w;
      s += v.x + v.y + v.z + v.w;
      q += v.x*v.x + v.y*v.y + v.z*v.z + v.w*v.w;
    }
    s += __shfl_xor(s, 1, 64); q += __shfl_xor(q, 1, 64);
    s += __shfl_xor(s, 2, 64); q += __shfl_xor(q, 2, 64);
    s += __shfl_xor(s, 4, 64); q += __shfl_xor(q, 4, 64);
    float mean = s * 0.00390625f;
    float rstd = rsqrtf(q * 0.00390625f - mean * mean + 1e-5f);
#pragma unroll
    for (int i = 0; i < 4; ++i) {
      const int col = cq + i * 8;
      u16x8 o;
#pragma unroll
      for (int j = 0; j < 8; ++j)
        o[j] = f2bf((vals[i*8+j] - mean) * rstd * g2[col+j] + bt2[col+j]);
      const int gran = col >> 3;
      *(u16x8*)((char*)Aln + row * 512 + ((gran ^ (row & 7)) << 4)) = o;
    }
  }

  f32x4 acc2[4][2];   // [tf][of]: oc = wid*32 + of*16 + l15
#pragma unroll
  for (int m = 0; m < 4; ++m)
#pragma unroll
    for (int n = 0; n < 2; ++n) acc2[m][n] = (f32x4){0.f, 0.f, 0.f, 0.f};
  f32x4 acc1[4];

#define MGEMM1(c)                                                                 \
  {                                                                               \
    _Pragma("unroll")                                                             \
    for (int tf = 0; tf < 4; ++tf) acc1[tf] = (f32x4){0.f, 0.f, 0.f, 0.f};        \
    const u16* w1base = w1t + (size_t)((c) * 128 + wid * 16) * 256;               \
    _Pragma("unroll")                                                             \
    for (int ks = 0; ks < 8; ++ks) {                                              \
      bf16x8 af = *(const bf16x8*)(w1base + (size_t)l15 * 256 + ks * 32 + g * 8); \
      bf16x8 bfr[4];                                                              \
      _Pragma("unroll")                                                           \
      for (int tf = 0; tf < 4; ++tf) {                                            \
        const int tok = tf * 16 + l15;                                            \
        const int gran = ks * 4 + g;                                              \
        bfr[tf] = *(const bf16x8*)&Aln[tok * 256 + ((gran ^ (tok & 7)) << 3)];    \
      }                                                                           \
      _Pragma("unroll")                                                           \
      for (int tf = 0; tf < 4; ++tf)                                              \
        acc1[tf] = __builtin_amdgcn_mfma_f32_16x16x32_bf16(af, bfr[tf], acc1[tf], 0, 0, 0); \
    }                                                                             \
  }

#define MPACK(c)                                                                  \
  {                                                                               \
    char* hdst = (char*)Hs[(c) & 1];                                              \
    const int hcl = wid * 16 + g * 4;                                             \
    const float b0 = fb1[(c) * 128 + hcl];                                        \
    const float b1 = fb1[(c) * 128 + hcl + 1];                                    \
    const float b2v = fb1[(c) * 128 + hcl + 2];                                   \
    const float b3 = fb1[(c) * 128 + hcl + 3];                                    \
    _Pragma("unroll")                                                             \
    for (int tf = 0; tf < 4; ++tf) {                                              \
      const int tok = tf * 16 + l15;                                              \
      float p0 = gelu_f(acc1[tf][0] + b0);                                        \
      float p1 = gelu_f(acc1[tf][1] + b1);                                        \
      float p2 = gelu_f(acc1[tf][2] + b2v);                                       \
      float p3 = gelu_f(acc1[tf][3] + b3);                                        \
      unsigned int pa, pb;                                                        \
      asm("v_cvt_pk_bf16_f32 %0, %1, %2" : "=v"(pa) : "v"(p0), "v"(p1));          \
      asm("v_cvt_pk_bf16_f32 %0, %1, %2" : "=v"(pb) : "v"(p2), "v"(p3));          \
      uint2 w; w.x = pa; w.y = pb;                                                \
      *(uint2*)(hdst + tok * 256 + (((hcl >> 3) ^ (tok & 7)) << 4) + ((hcl & 4) << 1)) = w; \
    }                                                                             \
  }

#define MGEMM2(c)                                                                 \
  {                                                                               \
    const u16* hsrc = Hs[(c) & 1];                                                \
    const u16* w2base = w2t + (size_t)(wid * 32) * 1024 + (c) * 128;              \
    _Pragma("unroll")                                                             \
    for (int hk = 0; hk < 4; ++hk) {                                              \
      bf16x8 ah[4], bw[2];                                                        \
      _Pragma("unroll")                                                           \
      for (int tf = 0; tf < 4; ++tf) {                                            \
        const int tok = tf * 16 + l15;                                            \
        const int gran = hk * 4 + g;                                              \
        ah[tf] = *(const bf16x8*)&hsrc[tok * 128 + ((gran ^ (tok & 7)) << 3)];    \
      }                                                                           \
      _Pragma("unroll")                                                           \
      for (int of = 0; of < 2; ++of)                                              \
        bw[of] = *(const bf16x8*)(w2base + (size_t)(of * 16 + l15) * 1024 + hk * 32 + g * 8); \
      _Pragma("unroll")                                                           \
      for (int tf = 0; tf < 4; ++tf)                                              \
        _Pragma("unroll")                                                         \
        for (int of = 0; of < 2; ++of)                                            \
          acc2[tf][of] = __builtin_amdgcn_mfma_f32_16x16x32_bf16(ah[tf], bw[of], acc2[tf][of], 0, 0, 0); \
    }                                                                             \
  }

  __syncthreads();           // Aln visible
  MGEMM1(0);
  MPACK(0);
  __syncthreads();
#pragma unroll
  for (int c = 1; c < 8; ++c) {
    MGEMM2(c - 1);           // reads Hs[(c-1)&1]  (RAW fenced by prev barrier)
    MGEMM1(c);               // independent (Aln + w1)
    MPACK(c);                // writes Hs[c&1] (WAR vs GEMM2(c-2) fenced by prev barrier)
    __syncthreads();
  }
  MGEMM2(7);
#undef MGEMM1
#undef MPACK
#undef MGEMM2

  // ---- epilogue: + fc2 bias + residual (in-place) ----
#pragma unroll
  for (int tf = 0; tf < 4; ++tf) {
#pragma unroll
    for (int of = 0; of < 2; ++of) {
      const int oc = wid * 32 + of * 16 + l15;
      const float bv = fb2[oc];
#pragma unroll
      for (int r = 0; r < 4; ++r) {
        const size_t off = (size_t)(t0 + tf * 16 + g * 4 + r) * 256 + oc;
        io[off] = acc2[tf][of][r] + bv + io[off];
      }
    }
  }
}

// ---------------- launch ----------------
extern "C" void kernel_launch(void* const* d_in, const int* in_sizes, int n_in,
                              void* d_out, int out_size, void* d_ws, size_t ws_size,
                              hipStream_t stream)
{
  const float* x      = (const float*)d_in[0];
  const float* qkv_w  = (const float*)d_in[1];
  const float* qkv_b  = (const float*)d_in[2];
  const float* proj_w = (const float*)d_in[3];
  const float* proj_b = (const float*)d_in[4];
  const float* rpb    = (const float*)d_in[5];
  const float* g1     = (const float*)d_in[6];
  const float* b1     = (const float*)d_in[7];
  const float* g2     = (const float*)d_in[8];
  const float* b2     = (const float*)d_in[9];
  const float* fc1_w  = (const float*)d_in[10];
  const float* fc1_b  = (const float*)d_in[11];
  const float* fc2_w  = (const float*)d_in[12];
  const float* fc2_b  = (const float*)d_in[13];
  float* out = (float*)d_out;
  char* ws = (char*)d_ws;

  // bf16 transposed weights (1.5 MB)
  u16* qkvT  = (u16*)ws;            // [768][256]
  u16* projT = qkvT + 196608;       // [256][256]
  u16* fc1T  = projT + 65536;       // [1024][256]
  u16* fc2T  = fc1T + 262144;       // [256][1024]
  char* pb = (char*)(fc2T + 262144);
  size_t used = 1572864ULL;
  size_t R = ws_size > used ? ws_size - used : 0;

  wconv_kernel<<<(196608 + 255) / 256, 256, 0, stream>>>(qkv_w, qkvT, 256, 768);
  wconv_kernel<<<(65536  + 255) / 256, 256, 0, stream>>>(proj_w, projT, 256, 256);
  wconv_kernel<<<(262144 + 255) / 256, 256, 0, stream>>>(fc1_w, fc1T, 256, 1024);
  wconv_kernel<<<(262144 + 255) / 256, 256, 0, stream>>>(fc2_w, fc2T, 1024, 256);

  // Chunk the front so each chunk's q/k/v (96 KB * Gc) fits per-XCD L2:
  // Gc=256 -> 24 MB total, ~3 MB/XCD < 4 MB L2. qln block w and awp block w
  // use identical grids, so they should land on the same XCD (round-robin).
  int Gc = 256;
  while (Gc > 2 && (size_t)Gc * 98304ULL > R) Gc >>= 1;

  u16* qb = (u16*)pb;
  u16* kb = qb + (size_t)Gc * 16384;
  u16* vb = kb + (size_t)Gc * 16384;   // stored transposed [hd][tok]

  for (int g0 = 0; g0 < NWIN_TOTAL; g0 += Gc) {
    qln_kernel<<<Gc, 1024, 0, stream>>>(x, g1, b1, qkvT, qkv_b, qb, kb, vb, g0);
    awp_kernel<<<Gc, 512, 0, stream>>>(qb, kb, vb, rpb, projT, proj_b, x, out, g0);
  }

  mlp_kernel<<<TOK_TOTAL / 64, 512, 0, stream>>>(out, fc1T, fc2T, fc1_b, fc2_b, g2, b2);
}

// Round 17
// 641.433 us; speedup vs baseline: 1.0453x; 1.0453x over previous
//
#include <hip/hip_runtime.h>
#include <math.h>

// Swin block: B=8 H=W=128 C=256 NH=8 HD=32 WS=8 SS=4, N=64 tokens/window,
// 2048 windows, 131072 tokens.

#define NWIN_TOTAL 2048
#define TOK_TOTAL  131072
#define SCALE_Q    0.17677669529663687f  // 32^-0.5
#define LOG2E      1.4426950408889634f

typedef unsigned short u16;
typedef __attribute__((ext_vector_type(4))) unsigned short u16x4;
typedef __attribute__((ext_vector_type(8))) unsigned short u16x8;
typedef __attribute__((ext_vector_type(8))) short bf16x8;   // MFMA A/B frag (4 VGPR)
typedef __attribute__((ext_vector_type(4))) float f32x4;    // MFMA C/D frag

#define AS1 __attribute__((address_space(1)))
#define AS3 __attribute__((address_space(3)))
#define GLOAD_LDS16(g, l) \
  __builtin_amdgcn_global_load_lds((const AS1 unsigned int*)(g), (AS3 unsigned int*)(l), 16, 0, 0)

__device__ __forceinline__ float bf2f(u16 u) {
  union { unsigned int i; float f; } c; c.i = ((unsigned int)u) << 16; return c.f;
}
__device__ __forceinline__ u16 f2bf(float f) {
  union { float f; unsigned int i; } c; c.f = f;
  return (u16)((c.i + 0x7fff + ((c.i >> 16) & 1)) >> 16);
}
__device__ __forceinline__ int regid3(int h) { return h < 120 ? 0 : (h < 124 ? 1 : 2); }
// tanh-form GELU: v*t/(t+1), t = exp2(v*(2*log2e*sqrt(2/pi))*(1+0.044715 v^2))
__device__ __forceinline__ float gelu_f(float v) {
  float t = exp2f(v * fmaf(v * v, 0.10294423f, 2.3022082f));
  return v * t * __builtin_amdgcn_rcpf(t + 1.0f);
}

// (window g, token n) -> flat token index in image space (shift applied)
__device__ __forceinline__ int win_tok_to_t(int g, int n) {
  int b = g >> 8, wi = g & 255;
  int wr = wi >> 4, wc = wi & 15;
  int hs = wr * 8 + (n >> 3), ws2 = wc * 8 + (n & 7);
  int h = (hs + 4) & 127, w = (ws2 + 4) & 127;
  return (b << 14) + (h << 7) + w;
}

// ---------------- weight convert + transpose: [K][N] f32 -> [N][K] bf16 ----------------
__global__ __launch_bounds__(256)
void wconv_kernel(const float* __restrict__ w, u16* __restrict__ wt, int K, int N)
{
  int i = blockIdx.x * 256 + threadIdx.x;
  if (i >= K * N) return;
  int k = i / N, n = i - k * N;
  wt[(size_t)n * K + k] = f2bf(w[i]);
}

// ---------------- fused LN1 + qkv GEMM: one block per window, 16 waves ----------------
__global__ __launch_bounds__(1024)
void qln_kernel(const float* __restrict__ x, const float* __restrict__ g1,
                const float* __restrict__ b1, const u16* __restrict__ qkvT,
                const float* __restrict__ qkv_b,
                u16* __restrict__ qb, u16* __restrict__ kb, u16* __restrict__ vb,
                int g0)
{
  __shared__ u16 Aln[16384];   // [64 tok][256 k] bf16, 16B-gran ^= tok&7 (32 KB)
  const int tid = threadIdx.x, wid = tid >> 6, lane = tid & 63;
  const int l15 = lane & 15, g = lane >> 4;
  const int bwi = blockIdx.x;
  const int gw = g0 + bwi;

  // ---- LN1 stage with shifted-window gather: 16 lanes per row, 16 cols each ----
  {
    const int row = tid >> 4;
    const int cq = (tid & 15) * 16;
    const int t = win_tok_to_t(gw, row);
    const float* src = x + (size_t)t * 256 + cq;
    float vals[16];
    float s = 0.f, q = 0.f;
#pragma unroll
    for (int i = 0; i < 4; ++i) {
      float4 v = ((const float4*)src)[i];
      vals[i*4] = v.x; vals[i*4+1] = v.y; vals[i*4+2] = v.z; vals[i*4+3] = v.w;
      s += v.x + v.y + v.z + v.w;
      q += v.x*v.x + v.y*v.y + v.z*v.z + v.w*v.w;
    }
    s += __shfl_xor(s, 1, 64); q += __shfl_xor(q, 1, 64);
    s += __shfl_xor(s, 2, 64); q += __shfl_xor(q, 2, 64);
    s += __shfl_xor(s, 4, 64); q += __shfl_xor(q, 4, 64);
    s += __shfl_xor(s, 8, 64); q += __shfl_xor(q, 8, 64);
    float mean = s * 0.00390625f;
    float rstd = rsqrtf(q * 0.00390625f - mean * mean + 1e-5f);
#pragma unroll
    for (int i = 0; i < 2; ++i) {
      const int col = cq + i * 8;
      u16x8 o;
#pragma unroll
      for (int j = 0; j < 8; ++j)
        o[j] = f2bf((vals[i*8+j] - mean) * rstd * g1[col+j] + b1[col+j]);
      const int gran = col >> 3;
      *(u16x8*)((char*)Aln + row * 512 + ((gran ^ (row & 7)) << 4)) = o;
    }
  }
  __syncthreads();

  // ---- GEMM: acc[m][n], row = tok (m*16+g*4+r), col = wid*48 + n*16 + l15 ----
  f32x4 acc[4][3];
#pragma unroll
  for (int m = 0; m < 4; ++m)
#pragma unroll
    for (int n = 0; n < 3; ++n) acc[m][n] = (f32x4){0.f, 0.f, 0.f, 0.f};
  const int colb = wid * 48;
#pragma unroll
  for (int ks = 0; ks < 8; ++ks) {
    bf16x8 af[4], bw[3];
#pragma unroll
    for (int m = 0; m < 4; ++m) {
      const int tok = m * 16 + l15;
      const int gran = ks * 4 + g;
      af[m] = *(const bf16x8*)&Aln[tok * 256 + ((gran ^ (tok & 7)) << 3)];
    }
#pragma unroll
    for (int n = 0; n < 3; ++n)
      bw[n] = *(const bf16x8*)(qkvT + (size_t)(colb + n * 16 + l15) * 256 + ks * 32 + g * 8);
#pragma unroll
    for (int m = 0; m < 4; ++m)
#pragma unroll
      for (int n = 0; n < 3; ++n)
        acc[m][n] = __builtin_amdgcn_mfma_f32_16x16x32_bf16(af[m], bw[n], acc[m][n], 0, 0, 0);
  }

  // ---- epilogue: +bias; q scaled token-major; k token-major; v transposed ----
#pragma unroll
  for (int n = 0; n < 3; ++n) {
    const int col16 = colb + n * 16;
    const float bv = qkv_b[col16 + l15];
    const int s = col16 >> 8, head = (col16 >> 5) & 7, hd = col16 & 31;
    if (s == 2) {
      const size_t obase = ((size_t)bwi << 14) + ((size_t)head << 11) + (size_t)(hd + l15) * 64;
#pragma unroll
      for (int m = 0; m < 4; ++m) {
        const int tok0 = m * 16 + g * 4;
        u16x4 pk;
#pragma unroll
        for (int r = 0; r < 4; ++r) pk[r] = f2bf(acc[m][n][r] + bv);
        *(u16x4*)&vb[obase + tok0] = pk;
      }
    } else {
      u16* qdst = (s == 0) ? qb : kb;
      const float scl = (s == 0) ? SCALE_Q * LOG2E : 1.f;
      const size_t obase = ((size_t)bwi << 14) + ((size_t)head << 11) + hd + l15;
#pragma unroll
      for (int m = 0; m < 4; ++m)
#pragma unroll
        for (int r = 0; r < 4; ++r) {
          const int tok = m * 16 + g * 4 + r;
          qdst[obase + ((size_t)tok << 5)] = f2bf((acc[m][n][r] + bv) * scl);
        }
    }
  }
}

// ---------------- fused attention + proj + shift-reverse + residual ----------------
// One block per window (8 waves = 8 heads), 512 threads.
__global__ __launch_bounds__(512)
void awp_kernel(const u16* __restrict__ qb, const u16* __restrict__ kb,
                const u16* __restrict__ vt, const float* __restrict__ rpb,
                const u16* __restrict__ pjT, const float* __restrict__ pjb,
                const float* __restrict__ x, float* __restrict__ out, int g0)
{
  __shared__ union {
    u16 pl[8][2048];     // per-wave P half-buffer [n 64][m 32] bf16, byte^=(n&3)<<4 (32 KB)
    u16 aoL[16384];      // [tok 64][ch 256] bf16, 16B-gran ^= tok&7 (32 KB)
    float rep[8192];     // [row 32][oc 256] f32, 16B-gran ^= row&3 (32 KB)
  } sb;
  __shared__ float rl[1800];   // rpb re-layout: [head][di+7][dj2+7], *LOG2E
  const int tid = threadIdx.x, hh = tid >> 6, lane = tid & 63;
  const int l15 = lane & 15, g = lane >> 4;
  const int bw = blockIdx.x;

  for (int i = tid; i < 1800; i += 512) {
    unsigned int h2 = (unsigned)i / 225u;
    unsigned int rem = (unsigned)i - h2 * 225u;
    unsigned int aa = rem / 15u, bb = rem - aa * 15u;
    rl[i] = rpb[(aa * 15u + 14u - bb) * 8u + h2] * LOG2E;
  }
  __syncthreads();

  const size_t base = ((size_t)(bw * 8 + hh)) << 11;

  // ---- S^T = K · Q^T ----
  bf16x8 qf[4], kf[4];
#pragma unroll
  for (int f = 0; f < 4; ++f) {
    qf[f] = *(const bf16x8*)(qb + base + (size_t)(f * 16 + l15) * 32 + g * 8);
    kf[f] = *(const bf16x8*)(kb + base + (size_t)(f * 16 + l15) * 32 + g * 8);
  }
  f32x4 acc[4][4];
#pragma unroll
  for (int mf = 0; mf < 4; ++mf)
#pragma unroll
    for (int nf = 0; nf < 4; ++nf) acc[mf][nf] = (f32x4){0.f, 0.f, 0.f, 0.f};
#pragma unroll
  for (int mf = 0; mf < 4; ++mf)
#pragma unroll
    for (int nf = 0; nf < 4; ++nf)
      acc[mf][nf] = __builtin_amdgcn_mfma_f32_16x16x32_bf16(kf[mf], qf[nf], acc[mf][nf], 0, 0, 0);

  // ---- bias + mask (log2 domain). m = mf*16 + g*4 + r ----
  const int gwin = g0 + bw;
  const int wrw = (gwin >> 4) & 15, wcw = gwin & 15;
  const bool edge = (wrw == 15) || (wcw == 15);
  const int i2b = g >> 1;
  const int j2b = (g & 1) * 4;
#pragma unroll
  for (int nf = 0; nf < 4; ++nf) {
    const int n = nf * 16 + l15;
    const int i1 = n >> 3, j1 = n & 7;
    const int rid1 = edge ? regid3(wrw * 8 + i1) * 3 + regid3(wcw * 8 + j1) : 0;
#pragma unroll
    for (int mf = 0; mf < 4; ++mf) {
      const int i2 = mf * 2 + i2b;
      const int ib = hh * 225 + (i1 - i2 + 7) * 15 + (j2b - j1 + 7);
      const int r2a = edge ? regid3(wrw * 8 + i2) * 3 : 0;
#pragma unroll
      for (int r = 0; r < 4; ++r) {
        float b = rl[ib + r];
        if (edge) {
          int rid2 = r2a + regid3(wcw * 8 + j2b + r);
          if (rid2 != rid1) b -= 144.2695f;
        }
        acc[mf][nf][r] += b;
      }
    }
  }

  // ---- softmax over m, per column n ----
  float inv[4];
#pragma unroll
  for (int nf = 0; nf < 4; ++nf) {
    float m0 = -1e30f;
#pragma unroll
    for (int mf = 0; mf < 4; ++mf)
#pragma unroll
      for (int r = 0; r < 4; ++r) m0 = fmaxf(m0, acc[mf][nf][r]);
    m0 = fmaxf(m0, __shfl_xor(m0, 16, 64));
    m0 = fmaxf(m0, __shfl_xor(m0, 32, 64));
    float s = 0.f;
#pragma unroll
    for (int mf = 0; mf < 4; ++mf)
#pragma unroll
      for (int r = 0; r < 4; ++r) {
        float p = exp2f(acc[mf][nf][r] - m0);
        acc[mf][nf][r] = p;
        s += p;
      }
    s += __shfl_xor(s, 16, 64);
    s += __shfl_xor(s, 32, 64);
    inv[nf] = 1.f / s;
  }

  // ---- O = P · V, P exchanged through per-wave half-buffer (m in 2 halves) ----
  bf16x8 vf[2][2];
#pragma unroll
  for (int df = 0; df < 2; ++df)
#pragma unroll
    for (int ks = 0; ks < 2; ++ks)
      vf[df][ks] = *(const bf16x8*)(vt + base + (size_t)(df * 16 + l15) * 64 + ks * 32 + g * 8);
  f32x4 accO[4][2];
#pragma unroll
  for (int nf = 0; nf < 4; ++nf)
#pragma unroll
    for (int df = 0; df < 2; ++df) accO[nf][df] = (f32x4){0.f, 0.f, 0.f, 0.f};
  char* plw = (char*)sb.pl[hh];
#pragma unroll
  for (int ks = 0; ks < 2; ++ks) {
#pragma unroll
    for (int nf = 0; nf < 4; ++nf) {
      const int n = nf * 16 + l15;
      const int swz = (n & 3) << 4;
#pragma unroll
      for (int mm = 0; mm < 2; ++mm) {
        const int mf = ks * 2 + mm;
        float p0 = acc[mf][nf][0] * inv[nf], p1 = acc[mf][nf][1] * inv[nf];
        float p2 = acc[mf][nf][2] * inv[nf], p3 = acc[mf][nf][3] * inv[nf];
        unsigned int pa, pb;
        asm("v_cvt_pk_bf16_f32 %0, %1, %2" : "=v"(pa) : "v"(p0), "v"(p1));
        asm("v_cvt_pk_bf16_f32 %0, %1, %2" : "=v"(pb) : "v"(p2), "v"(p3));
        uint2 w; w.x = pa; w.y = pb;
        *(uint2*)(plw + ((n * 64 + mm * 32 + g * 8) ^ swz)) = w;
      }
    }
#pragma unroll
    for (int nf = 0; nf < 4; ++nf) {
      const int n = nf * 16 + l15;
      const int swz = (n & 3) << 4;
      bf16x8 pf = *(const bf16x8*)(plw + ((n * 64 + g * 16) ^ swz));
#pragma unroll
      for (int df = 0; df < 2; ++df)
        accO[nf][df] = __builtin_amdgcn_mfma_f32_16x16x32_bf16(pf, vf[df][ks], accO[nf][df], 0, 0, 0);
    }
  }

  // ---- pack O into aoL[tok][ch] (aliases pl; all PV reads done first) ----
  __syncthreads();
#pragma unroll
  for (int nf = 0; nf < 4; ++nf)
#pragma unroll
    for (int r = 0; r < 4; ++r) {
      const int tok = nf * 16 + g * 4 + r;
#pragma unroll
      for (int df = 0; df < 2; ++df) {
        const int ch = hh * 32 + df * 16 + l15;
        *(u16*)((char*)sb.aoL + tok * 512 + ((((ch >> 3) ^ (tok & 7))) << 4) + (ch & 7) * 2) =
            f2bf(accO[nf][df][r]);
      }
    }
  __syncthreads();

  // ---- prefetch residual x rows into registers (hidden under proj GEMM) ----
  float4 xv[2][4];
  {
    const int rowl = tid >> 4, coll = (tid & 15) * 16;
#pragma unroll
    for (int hp = 0; hp < 2; ++hp) {
      const int t = win_tok_to_t(g0 + bw, hp * 32 + rowl);
      const float* xs = x + (size_t)t * 256 + coll;
#pragma unroll
      for (int i = 0; i < 4; ++i) xv[hp][i] = ((const float4*)xs)[i];
    }
  }

  // ---- proj GEMM: wave hh owns oc slice [hh*32, +32); K = 256 ----
  f32x4 pacc[4][2];
#pragma unroll
  for (int mf = 0; mf < 4; ++mf)
#pragma unroll
    for (int of = 0; of < 2; ++of) pacc[mf][of] = (f32x4){0.f, 0.f, 0.f, 0.f};
  const u16* pB = pjT + (size_t)(hh * 32) * 256;
#pragma unroll
  for (int ks = 0; ks < 8; ++ks) {
    bf16x8 af[4], bwf[2];
#pragma unroll
    for (int mf = 0; mf < 4; ++mf) {
      const int tok = mf * 16 + l15;
      af[mf] = *(const bf16x8*)((char*)sb.aoL + tok * 512 + (((ks * 4 + g) ^ (tok & 7)) << 4));
    }
#pragma unroll
    for (int of = 0; of < 2; ++of)
      bwf[of] = *(const bf16x8*)(pB + (size_t)(of * 16 + l15) * 256 + ks * 32 + g * 8);
#pragma unroll
    for (int mf = 0; mf < 4; ++mf)
#pragma unroll
      for (int of = 0; of < 2; ++of)
        pacc[mf][of] = __builtin_amdgcn_mfma_f32_16x16x32_bf16(af[mf], bwf[of], pacc[mf][of], 0, 0, 0);
  }

  // ---- epilogue: two 32-row halves through rep; coalesced x+residual scatter ----
#pragma unroll
  for (int hp = 0; hp < 2; ++hp) {
    __syncthreads();
#pragma unroll
    for (int mm = 0; mm < 2; ++mm) {
      const int mf = hp * 2 + mm;
#pragma unroll
      for (int of = 0; of < 2; ++of) {
        const int oc = hh * 32 + of * 16 + l15;
        const float bv = pjb[oc];
#pragma unroll
        for (int r = 0; r < 4; ++r) {
          const int row = mm * 16 + g * 4 + r;
          *(float*)((char*)sb.rep + ((row * 1024 + oc * 4) ^ ((row & 3) << 4))) =
              pacc[mf][of][r] + bv;
        }
      }
    }
    __syncthreads();
    const int rowl = tid >> 4, coll = (tid & 15) * 16;
    const int tok = hp * 32 + rowl;
    const int t = win_tok_to_t(g0 + bw, tok);
    float* od = out + (size_t)t * 256 + coll;
#pragma unroll
    for (int i = 0; i < 4; ++i) {
      float4 rv = *(const float4*)((char*)sb.rep +
                    ((rowl * 1024 + (coll + i * 4) * 4) ^ ((rowl & 3) << 4)));
      ((float4*)od)[i] = make_float4(rv.x + xv[hp][i].x, rv.y + xv[hp][i].y,
                                     rv.z + xv[hp][i].z, rv.w + xv[hp][i].w);
    }
  }
}

// ---------------- fused MLP v8: v6 8-wave split + single barrier/chunk (dbuf Hs) ----------------
// 64 tokens/block, 8 waves (512 thr), 64 KB LDS (same 2-block slot as 48 KB).
// Per chunk: { GEMM2(c-1) || GEMM1(c) -> GELU+pack->Hs[c&1] -> BAR }  (9 barriers total).
__global__ __launch_bounds__(512)
void mlp_kernel(float* io, const u16* __restrict__ w1t, const u16* __restrict__ w2t,
                const float* __restrict__ fb1, const float* __restrict__ fb2,
                const float* __restrict__ g2, const float* __restrict__ bt2)
{
  __shared__ u16 Aln[16384];    // [64 tok][256 k] bf16, 16B-gran ^= tok&7  (32 KB)
  __shared__ u16 Hs[2][8192];   // dbuf [64 tok][128 h] bf16, gran ^= tok&7 (32 KB)
  const int tid = threadIdx.x, wid = tid >> 6, lane = tid & 63;
  const int l15 = lane & 15, g = lane >> 4;
  const int t0 = blockIdx.x * 64;

  // ---- stage Aln with fused LN2 (8 lanes per row, 32 cols each) ----
  {
    const int row = tid >> 3;          // 0..63
    const int cq = (tid & 7) * 32;
    const float* src = io + (size_t)(t0 + row) * 256 + cq;
    float vals[32];
    float s = 0.f, q = 0.f;
#pragma unroll
    for (int i = 0; i < 8; ++i) {
      float4 v = ((const float4*)src)[i];
      vals[i*4] = v.x; vals[i*4+1] = v.y; vals[i*4+2] = v.z; vals[i*4+3] = v.w;
      s += v.x + v.y + v.z + v.w;
      q += v.x*v.x + v.y*v.y + v.z*v.z + v.w*v.w;
    }
    s += __shfl_xor(s, 1, 64); q += __shfl_xor(q, 1, 64);
    s += __shfl_xor(s, 2, 64); q += __shfl_xor(q, 2, 64);
    s += __shfl_xor(s, 4, 64); q += __shfl_xor(q, 4, 64);
    float mean = s * 0.00390625f;
    float rstd = rsqrtf(q * 0.00390625f - mean * mean + 1e-5f);
#pragma unroll
    for (int i = 0; i < 4; ++i) {
      const int col = cq + i * 8;
      u16x8 o;
#pragma unroll
      for (int j = 0; j < 8; ++j)
        o[j] = f2bf((vals[i*8+j] - mean) * rstd * g2[col+j] + bt2[col+j]);
      const int gran = col >> 3;
      *(u16x8*)((char*)Aln + row * 512 + ((gran ^ (row & 7)) << 4)) = o;
    }
  }

  f32x4 acc2[4][2];   // [tf][of]: oc = wid*32 + of*16 + l15
#pragma unroll
  for (int m = 0; m < 4; ++m)
#pragma unroll
    for (int n = 0; n < 2; ++n) acc2[m][n] = (f32x4){0.f, 0.f, 0.f, 0.f};
  f32x4 acc1[4];

#define MGEMM1(c)                                                                 \
  {                                                                               \
    _Pragma("unroll")                                                             \
    for (int tf = 0; tf < 4; ++tf) acc1[tf] = (f32x4){0.f, 0.f, 0.f, 0.f};        \
    const u16* w1base = w1t + (size_t)((c) * 128 + wid * 16) * 256;               \
    _Pragma("unroll")                                                             \
    for (int ks = 0; ks < 8; ++ks) {                                              \
      bf16x8 af = *(const bf16x8*)(w1base + (size_t)l15 * 256 + ks * 32 + g * 8); \
      bf16x8 bfr[4];                                                              \
      _Pragma("unroll")                                                           \
      for (int tf = 0; tf < 4; ++tf) {                                            \
        const int tok = tf * 16 + l15;                                            \
        const int gran = ks * 4 + g;                                              \
        bfr[tf] = *(const bf16x8*)&Aln[tok * 256 + ((gran ^ (tok & 7)) << 3)];    \
      }                                                                           \
      _Pragma("unroll")                                                           \
      for (int tf = 0; tf < 4; ++tf)                                              \
        acc1[tf] = __builtin_amdgcn_mfma_f32_16x16x32_bf16(af, bfr[tf], acc1[tf], 0, 0, 0); \
    }                                                                             \
  }

#define MPACK(c)                                                                  \
  {                                                                               \
    char* hdst = (char*)Hs[(c) & 1];                                              \
    const int hcl = wid * 16 + g * 4;                                             \
    const float b0 = fb1[(c) * 128 + hcl];                                        \
    const float b1 = fb1[(c) * 128 + hcl + 1];                                    \
    const float b2v = fb1[(c) * 128 + hcl + 2];                                   \
    const float b3 = fb1[(c) * 128 + hcl + 3];                                    \
    _Pragma("unroll")                                                             \
    for (int tf = 0; tf < 4; ++tf) {                                              \
      const int tok = tf * 16 + l15;                                              \
      float p0 = gelu_f(acc1[tf][0] + b0);                                        \
      float p1 = gelu_f(acc1[tf][1] + b1);                                        \
      float p2 = gelu_f(acc1[tf][2] + b2v);                                       \
      float p3 = gelu_f(acc1[tf][3] + b3);                                        \
      unsigned int pa, pb;                                                        \
      asm("v_cvt_pk_bf16_f32 %0, %1, %2" : "=v"(pa) : "v"(p0), "v"(p1));          \
      asm("v_cvt_pk_bf16_f32 %0, %1, %2" : "=v"(pb) : "v"(p2), "v"(p3));          \
      uint2 w; w.x = pa; w.y = pb;                                                \
      *(uint2*)(hdst + tok * 256 + (((hcl >> 3) ^ (tok & 7)) << 4) + ((hcl & 4) << 1)) = w; \
    }                                                                             \
  }

#define MGEMM2(c)                                                                 \
  {                                                                               \
    const u16* hsrc = Hs[(c) & 1];                                                \
    const u16* w2base = w2t + (size_t)(wid * 32) * 1024 + (c) * 128;              \
    _Pragma("unroll")                                                             \
    for (int hk = 0; hk < 4; ++hk) {                                              \
      bf16x8 ah[4], bw[2];                                                        \
      _Pragma("unroll")                                                           \
      for (int tf = 0; tf < 4; ++tf) {                                            \
        const int tok = tf * 16 + l15;                                            \
        const int gran = hk * 4 + g;                                              \
        ah[tf] = *(const bf16x8*)&hsrc[tok * 128 + ((gran ^ (tok & 7)) << 3)];    \
      }                                                                           \
      _Pragma("unroll")                                                           \
      for (int of = 0; of < 2; ++of)                                              \
        bw[of] = *(const bf16x8*)(w2base + (size_t)(of * 16 + l15) * 1024 + hk * 32 + g * 8); \
      _Pragma("unroll")                                                           \
      for (int tf = 0; tf < 4; ++tf)                                              \
        _Pragma("unroll")                                                         \
        for (int of = 0; of < 2; ++of)                                            \
          acc2[tf][of] = __builtin_amdgcn_mfma_f32_16x16x32_bf16(ah[tf], bw[of], acc2[tf][of], 0, 0, 0); \
    }                                                                             \
  }

  __syncthreads();           // Aln visible
  MGEMM1(0);
  MPACK(0);
  __syncthreads();
#pragma unroll
  for (int c = 1; c < 8; ++c) {
    MGEMM2(c - 1);           // reads Hs[(c-1)&1]  (RAW fenced by prev barrier)
    MGEMM1(c);               // independent (Aln + w1)
    MPACK(c);                // writes Hs[c&1] (WAR vs GEMM2(c-2) fenced by prev barrier)
    __syncthreads();
  }
  MGEMM2(7);
#undef MGEMM1
#undef MPACK
#undef MGEMM2

  // ---- epilogue: + fc2 bias + residual (in-place) ----
#pragma unroll
  for (int tf = 0; tf < 4; ++tf) {
#pragma unroll
    for (int of = 0; of < 2; ++of) {
      const int oc = wid * 32 + of * 16 + l15;
      const float bv = fb2[oc];
#pragma unroll
      for (int r = 0; r < 4; ++r) {
        const size_t off = (size_t)(t0 + tf * 16 + g * 4 + r) * 256 + oc;
        io[off] = acc2[tf][of][r] + bv + io[off];
      }
    }
  }
}

// ---------------- launch ----------------
extern "C" void kernel_launch(void* const* d_in, const int* in_sizes, int n_in,
                              void* d_out, int out_size, void* d_ws, size_t ws_size,
                              hipStream_t stream)
{
  const float* x      = (const float*)d_in[0];
  const float* qkv_w  = (const float*)d_in[1];
  const float* qkv_b  = (const float*)d_in[2];
  const float* proj_w = (const float*)d_in[3];
  const float* proj_b = (const float*)d_in[4];
  const float* rpb    = (const float*)d_in[5];
  const float* g1     = (const float*)d_in[6];
  const float* b1     = (const float*)d_in[7];
  const float* g2     = (const float*)d_in[8];
  const float* b2     = (const float*)d_in[9];
  const float* fc1_w  = (const float*)d_in[10];
  const float* fc1_b  = (const float*)d_in[11];
  const float* fc2_w  = (const float*)d_in[12];
  const float* fc2_b  = (const float*)d_in[13];
  float* out = (float*)d_out;
  char* ws = (char*)d_ws;

  // bf16 transposed weights (1.5 MB)
  u16* qkvT  = (u16*)ws;            // [768][256]
  u16* projT = qkvT + 196608;       // [256][256]
  u16* fc1T  = projT + 65536;       // [1024][256]
  u16* fc2T  = fc1T + 262144;       // [256][1024]
  char* pb = (char*)(fc2T + 262144);
  size_t used = 1572864ULL;
  size_t R = ws_size > used ? ws_size - used : 0;

  wconv_kernel<<<(196608 + 255) / 256, 256, 0, stream>>>(qkv_w, qkvT, 256, 768);
  wconv_kernel<<<(65536  + 255) / 256, 256, 0, stream>>>(proj_w, projT, 256, 256);
  wconv_kernel<<<(262144 + 255) / 256, 256, 0, stream>>>(fc1_w, fc1T, 256, 1024);
  wconv_kernel<<<(262144 + 255) / 256, 256, 0, stream>>>(fc2_w, fc2T, 1024, 256);

  // attention-phase scratch per window: q/k/v 3*32K = 96K
  int Gc = 2048;
  while (Gc > 2 && (size_t)Gc * 98304ULL > R) Gc >>= 1;

  u16* qb = (u16*)pb;
  u16* kb = qb + (size_t)Gc * 16384;
  u16* vb = kb + (size_t)Gc * 16384;   // stored transposed [hd][tok]

  for (int g0 = 0; g0 < NWIN_TOTAL; g0 += Gc) {
    qln_kernel<<<Gc, 1024, 0, stream>>>(x, g1, b1, qkvT, qkv_b, qb, kb, vb, g0);
    awp_kernel<<<Gc, 512, 0, stream>>>(qb, kb, vb, rpb, projT, proj_b, x, out, g0);
  }

  mlp_kernel<<<TOK_TOTAL / 64, 512, 0, stream>>>(out, fc1T, fc2T, fc1_b, fc2_b, g2, b2);
}

// Round 18
// 572.641 us; speedup vs baseline: 1.1708x; 1.1201x over previous
//
#include <hip/hip_runtime.h>
#include <math.h>

// Swin block: B=8 H=W=128 C=256 NH=8 HD=32 WS=8 SS=4, N=64 tokens/window,
// 2048 windows, 131072 tokens.

#define NWIN_TOTAL 2048
#define TOK_TOTAL  131072
#define SCALE_Q    0.17677669529663687f  // 32^-0.5
#define LOG2E      1.4426950408889634f

typedef unsigned short u16;
typedef __attribute__((ext_vector_type(4))) unsigned short u16x4;
typedef __attribute__((ext_vector_type(8))) unsigned short u16x8;
typedef __attribute__((ext_vector_type(8))) short bf16x8;   // MFMA A/B frag (4 VGPR)
typedef __attribute__((ext_vector_type(4))) float f32x4;    // MFMA C/D frag

__device__ __forceinline__ float bf2f(u16 u) {
  union { unsigned int i; float f; } c; c.i = ((unsigned int)u) << 16; return c.f;
}
__device__ __forceinline__ u16 f2bf(float f) {
  union { float f; unsigned int i; } c; c.f = f;
  return (u16)((c.i + 0x7fff + ((c.i >> 16) & 1)) >> 16);
}
__device__ __forceinline__ int regid3(int h) { return h < 120 ? 0 : (h < 124 ? 1 : 2); }
// tanh-form GELU: v*t/(t+1), t = exp2(v*(2*log2e*sqrt(2/pi))*(1+0.044715 v^2))
__device__ __forceinline__ float gelu_f(float v) {
  float t = exp2f(v * fmaf(v * v, 0.10294423f, 2.3022082f));
  return v * t * __builtin_amdgcn_rcpf(t + 1.0f);
}

// (window g, token n) -> flat token index in image space (shift applied)
__device__ __forceinline__ int win_tok_to_t(int g, int n) {
  int b = g >> 8, wi = g & 255;
  int wr = wi >> 4, wc = wi & 15;
  int hs = wr * 8 + (n >> 3), ws2 = wc * 8 + (n & 7);
  int h = (hs + 4) & 127, w = (ws2 + 4) & 127;
  return (b << 14) + (h << 7) + w;
}

// ---------------- weight convert + transpose: [K][N] f32 -> [N][K] bf16 ----------------
__global__ __launch_bounds__(256)
void wconv_kernel(const float* __restrict__ w, u16* __restrict__ wt, int K, int N)
{
  int i = blockIdx.x * 256 + threadIdx.x;
  if (i >= K * N) return;
  int k = i / N, n = i - k * N;
  wt[(size_t)n * K + k] = f2bf(w[i]);
}

// ---------------- fully fused front: LN1 + qkv + attention + proj + residual ----------------
// One block per window, 16 waves (1024 thr), ~135 KB LDS. Q/K/V never touch HBM.
__global__ __launch_bounds__(1024)
void fawp_kernel(const float* __restrict__ x, const float* __restrict__ g1,
                 const float* __restrict__ b1, const u16* __restrict__ qkvT,
                 const float* __restrict__ qkv_b, const float* __restrict__ rpb,
                 const u16* __restrict__ pjT, const float* __restrict__ pjb,
                 float* __restrict__ out)
{
  __shared__ u16 QL[8][2048];   // [head][tok 64][hd 32], byte^=((tok>>1)&3)<<4  (32 KB)
  __shared__ u16 KL[8][2048];   // same layout as QL                              (32 KB)
  __shared__ u16 VL[8][2048];   // [head][hd 32][tok 64], byte^=((hd&7)<<4)       (32 KB)
  __shared__ union {
    u16 Aln[16384];      // [64 tok][256 k] bf16, 16B-gran ^= tok&7 (32 KB)
    u16 pl[16][1024];    // per-wave P half-buffer [32 n][32 m] bf16 (32 KB)
    u16 aoL[16384];      // [tok 64][ch 256] bf16 (32 KB)
    float rep[8192];     // [row 32][oc 256] f32 (32 KB)
  } sb;
  __shared__ float rl[1800];    // rpb re-layout: [head][di+7][dj2+7], *LOG2E

  const int tid = threadIdx.x, wid = tid >> 6, lane = tid & 63;
  const int l15 = lane & 15, g = lane >> 4;
  const int gw = blockIdx.x;

  for (int i = tid; i < 1800; i += 1024) {
    unsigned int h2 = (unsigned)i / 225u;
    unsigned int rem = (unsigned)i - h2 * 225u;
    unsigned int aa = rem / 15u, bb = rem - aa * 15u;
    rl[i] = rpb[(aa * 15u + 14u - bb) * 8u + h2] * LOG2E;
  }

  // ---- phase A: LN1 stage with shifted-window gather -> Aln ----
  {
    const int row = tid >> 4;
    const int cq = (tid & 15) * 16;
    const int t = win_tok_to_t(gw, row);
    const float* src = x + (size_t)t * 256 + cq;
    float vals[16];
    float s = 0.f, q = 0.f;
#pragma unroll
    for (int i = 0; i < 4; ++i) {
      float4 v = ((const float4*)src)[i];
      vals[i*4] = v.x; vals[i*4+1] = v.y; vals[i*4+2] = v.z; vals[i*4+3] = v.w;
      s += v.x + v.y + v.z + v.w;
      q += v.x*v.x + v.y*v.y + v.z*v.z + v.w*v.w;
    }
    s += __shfl_xor(s, 1, 64); q += __shfl_xor(q, 1, 64);
    s += __shfl_xor(s, 2, 64); q += __shfl_xor(q, 2, 64);
    s += __shfl_xor(s, 4, 64); q += __shfl_xor(q, 4, 64);
    s += __shfl_xor(s, 8, 64); q += __shfl_xor(q, 8, 64);
    float mean = s * 0.00390625f;
    float rstd = rsqrtf(q * 0.00390625f - mean * mean + 1e-5f);
#pragma unroll
    for (int i = 0; i < 2; ++i) {
      const int col = cq + i * 8;
      u16x8 o;
#pragma unroll
      for (int j = 0; j < 8; ++j)
        o[j] = f2bf((vals[i*8+j] - mean) * rstd * g1[col+j] + b1[col+j]);
      const int gran = col >> 3;
      *(u16x8*)((char*)sb.Aln + row * 512 + ((gran ^ (row & 7)) << 4)) = o;
    }
  }
  __syncthreads();

  // ---- phase B: qkv GEMM; wave owns 48 of 768 cols ----
  {
    f32x4 acc[4][3];
#pragma unroll
    for (int m = 0; m < 4; ++m)
#pragma unroll
      for (int n = 0; n < 3; ++n) acc[m][n] = (f32x4){0.f, 0.f, 0.f, 0.f};
    const int colb = wid * 48;
#pragma unroll
    for (int ks = 0; ks < 8; ++ks) {
      bf16x8 af[4], bw[3];
#pragma unroll
      for (int m = 0; m < 4; ++m) {
        const int tok = m * 16 + l15;
        const int gran = ks * 4 + g;
        af[m] = *(const bf16x8*)&sb.Aln[tok * 256 + ((gran ^ (tok & 7)) << 3)];
      }
#pragma unroll
      for (int n = 0; n < 3; ++n)
        bw[n] = *(const bf16x8*)(qkvT + (size_t)(colb + n * 16 + l15) * 256 + ks * 32 + g * 8);
#pragma unroll
      for (int m = 0; m < 4; ++m)
#pragma unroll
        for (int n = 0; n < 3; ++n)
          acc[m][n] = __builtin_amdgcn_mfma_f32_16x16x32_bf16(af[m], bw[n], acc[m][n], 0, 0, 0);
    }

    // epilogue -> LDS Q/K/V (swizzled)
#pragma unroll
    for (int n = 0; n < 3; ++n) {
      const int col16 = colb + n * 16;
      const float bv = qkv_b[col16 + l15];
      const int s = col16 >> 8, head = (col16 >> 5) & 7, hd = col16 & 31;
      if (s == 2) {
        const int row = hd + l15;      // V row = head-dim
        char* vdst = (char*)VL[head] + row * 128;
        const int sw = (row & 7) << 4;
#pragma unroll
        for (int m = 0; m < 4; ++m) {
          const int tok0 = m * 16 + g * 4;
          u16x4 pk;
#pragma unroll
          for (int r = 0; r < 4; ++r) pk[r] = f2bf(acc[m][n][r] + bv);
          *(u16x4*)(vdst + ((tok0 * 2) ^ sw)) = pk;
        }
      } else {
        char* dstL = (char*)((s == 0) ? QL[head] : KL[head]);
        const float scl = (s == 0) ? SCALE_Q * LOG2E : 1.f;
        const int cb2 = (hd + l15) * 2;
#pragma unroll
        for (int m = 0; m < 4; ++m)
#pragma unroll
          for (int r = 0; r < 4; ++r) {
            const int tok = m * 16 + g * 4 + r;
            *(u16*)(dstL + tok * 64 + (cb2 ^ (((tok >> 1) & 3) << 4))) =
                f2bf((acc[m][n][r] + bv) * scl);
          }
      }
    }
  }
  __syncthreads();

  // ---- phase C: attention; wave = (head hh, n-half) ----
  const int hh = wid & 7, half = wid >> 3;
  f32x4 accO[2][2];
  {
    // S^T = K · Q^T (n restricted to this wave's 32-col half)
    bf16x8 qf[2], kf[4];
#pragma unroll
    for (int nfl = 0; nfl < 2; ++nfl) {
      const int n = half * 32 + nfl * 16 + l15;
      qf[nfl] = *(const bf16x8*)((char*)QL[hh] + n * 64 + ((g * 16) ^ (((n >> 1) & 3) << 4)));
    }
#pragma unroll
    for (int f = 0; f < 4; ++f) {
      const int m = f * 16 + l15;
      kf[f] = *(const bf16x8*)((char*)KL[hh] + m * 64 + ((g * 16) ^ (((m >> 1) & 3) << 4)));
    }
    f32x4 acc[4][2];
#pragma unroll
    for (int mf = 0; mf < 4; ++mf)
#pragma unroll
      for (int nfl = 0; nfl < 2; ++nfl) acc[mf][nfl] = (f32x4){0.f, 0.f, 0.f, 0.f};
#pragma unroll
    for (int mf = 0; mf < 4; ++mf)
#pragma unroll
      for (int nfl = 0; nfl < 2; ++nfl)
        acc[mf][nfl] = __builtin_amdgcn_mfma_f32_16x16x32_bf16(kf[mf], qf[nfl], acc[mf][nfl], 0, 0, 0);

    // bias + mask (log2 domain). m = mf*16 + g*4 + r
    const int wrw = (gw >> 4) & 15, wcw = gw & 15;
    const bool edge = (wrw == 15) || (wcw == 15);
    const int i2b = g >> 1;
    const int j2b = (g & 1) * 4;
#pragma unroll
    for (int nfl = 0; nfl < 2; ++nfl) {
      const int n = half * 32 + nfl * 16 + l15;
      const int i1 = n >> 3, j1 = n & 7;
      const int rid1 = edge ? regid3(wrw * 8 + i1) * 3 + regid3(wcw * 8 + j1) : 0;
#pragma unroll
      for (int mf = 0; mf < 4; ++mf) {
        const int i2 = mf * 2 + i2b;
        const int ib = hh * 225 + (i1 - i2 + 7) * 15 + (j2b - j1 + 7);
        const int r2a = edge ? regid3(wrw * 8 + i2) * 3 : 0;
#pragma unroll
        for (int r = 0; r < 4; ++r) {
          float b = rl[ib + r];
          if (edge) {
            int rid2 = r2a + regid3(wcw * 8 + j2b + r);
            if (rid2 != rid1) b -= 144.2695f;
          }
          acc[mf][nfl][r] += b;
        }
      }
    }

    // softmax over m, per column n
    float inv[2];
#pragma unroll
    for (int nfl = 0; nfl < 2; ++nfl) {
      float m0 = -1e30f;
#pragma unroll
      for (int mf = 0; mf < 4; ++mf)
#pragma unroll
        for (int r = 0; r < 4; ++r) m0 = fmaxf(m0, acc[mf][nfl][r]);
      m0 = fmaxf(m0, __shfl_xor(m0, 16, 64));
      m0 = fmaxf(m0, __shfl_xor(m0, 32, 64));
      float s = 0.f;
#pragma unroll
      for (int mf = 0; mf < 4; ++mf)
#pragma unroll
        for (int r = 0; r < 4; ++r) {
          float p = exp2f(acc[mf][nfl][r] - m0);
          acc[mf][nfl][r] = p;
          s += p;
        }
      s += __shfl_xor(s, 16, 64);
      s += __shfl_xor(s, 32, 64);
      inv[nfl] = 1.f / s;
    }

    // O = P · V via per-wave pl half-buffer
    bf16x8 vf[2][2];
#pragma unroll
    for (int df = 0; df < 2; ++df)
#pragma unroll
      for (int ks = 0; ks < 2; ++ks) {
        const int row = df * 16 + l15;
        vf[df][ks] = *(const bf16x8*)((char*)VL[hh] + row * 128 +
                       ((ks * 64 + g * 16) ^ ((row & 7) << 4)));
      }
#pragma unroll
    for (int nfl = 0; nfl < 2; ++nfl)
#pragma unroll
      for (int df = 0; df < 2; ++df) accO[nfl][df] = (f32x4){0.f, 0.f, 0.f, 0.f};
    char* plw = (char*)sb.pl[wid];
#pragma unroll
    for (int ks = 0; ks < 2; ++ks) {
#pragma unroll
      for (int nfl = 0; nfl < 2; ++nfl) {
        const int nloc = nfl * 16 + l15;
        const int swz = (nloc & 3) << 4;
#pragma unroll
        for (int mm = 0; mm < 2; ++mm) {
          const int mf = ks * 2 + mm;
          float p0 = acc[mf][nfl][0] * inv[nfl], p1 = acc[mf][nfl][1] * inv[nfl];
          float p2 = acc[mf][nfl][2] * inv[nfl], p3 = acc[mf][nfl][3] * inv[nfl];
          unsigned int pa, pb;
          asm("v_cvt_pk_bf16_f32 %0, %1, %2" : "=v"(pa) : "v"(p0), "v"(p1));
          asm("v_cvt_pk_bf16_f32 %0, %1, %2" : "=v"(pb) : "v"(p2), "v"(p3));
          uint2 w; w.x = pa; w.y = pb;
          *(uint2*)(plw + ((nloc * 64 + mm * 32 + g * 8) ^ swz)) = w;
        }
      }
#pragma unroll
      for (int nfl = 0; nfl < 2; ++nfl) {
        const int nloc = nfl * 16 + l15;
        const int swz = (nloc & 3) << 4;
        bf16x8 pf = *(const bf16x8*)(plw + ((nloc * 64 + g * 16) ^ swz));
#pragma unroll
        for (int df = 0; df < 2; ++df)
          accO[nfl][df] = __builtin_amdgcn_mfma_f32_16x16x32_bf16(pf, vf[df][ks], accO[nfl][df], 0, 0, 0);
      }
    }
  }

  // ---- pack O into aoL[tok][ch] (aliases pl; all PV reads done first) ----
  __syncthreads();
#pragma unroll
  for (int nfl = 0; nfl < 2; ++nfl)
#pragma unroll
    for (int r = 0; r < 4; ++r) {
      const int tok = half * 32 + nfl * 16 + g * 4 + r;
#pragma unroll
      for (int df = 0; df < 2; ++df) {
        const int ch = hh * 32 + df * 16 + l15;
        *(u16*)((char*)sb.aoL + tok * 512 + ((((ch >> 3) ^ (tok & 7))) << 4) + (ch & 7) * 2) =
            f2bf(accO[nfl][df][r]);
      }
    }
  __syncthreads();

  // ---- prefetch residual x rows into registers (hidden under proj GEMM) ----
  float4 xv[2][2];
  {
    const int prow = tid >> 5, pcolb = (tid & 31) * 8;
#pragma unroll
    for (int hp = 0; hp < 2; ++hp) {
      const int t = win_tok_to_t(gw, hp * 32 + prow);
      const float* xs = x + (size_t)t * 256 + pcolb;
      xv[hp][0] = ((const float4*)xs)[0];
      xv[hp][1] = ((const float4*)xs)[1];
    }
  }

  // ---- proj GEMM: wave owns oc slice [wid*16, +16); K = 256 ----
  f32x4 pacc[4];
#pragma unroll
  for (int mf = 0; mf < 4; ++mf) pacc[mf] = (f32x4){0.f, 0.f, 0.f, 0.f};
  {
    const u16* pB = pjT + (size_t)(wid * 16 + l15) * 256;
#pragma unroll
    for (int ks = 0; ks < 8; ++ks) {
      bf16x8 af[4];
#pragma unroll
      for (int mf = 0; mf < 4; ++mf) {
        const int tok = mf * 16 + l15;
        af[mf] = *(const bf16x8*)((char*)sb.aoL + tok * 512 + (((ks * 4 + g) ^ (tok & 7)) << 4));
      }
      bf16x8 bwf = *(const bf16x8*)(pB + ks * 32 + g * 8);
#pragma unroll
      for (int mf = 0; mf < 4; ++mf)
        pacc[mf] = __builtin_amdgcn_mfma_f32_16x16x32_bf16(af[mf], bwf, pacc[mf], 0, 0, 0);
    }
  }

  // ---- epilogue: two 32-row halves through rep; coalesced x+residual scatter ----
#pragma unroll
  for (int hp = 0; hp < 2; ++hp) {
    __syncthreads();
    {
      const int oc = wid * 16 + l15;
      const float bv = pjb[oc];
#pragma unroll
      for (int mm = 0; mm < 2; ++mm) {
        const int mf = hp * 2 + mm;
#pragma unroll
        for (int r = 0; r < 4; ++r) {
          const int row = mm * 16 + g * 4 + r;
          *(float*)((char*)sb.rep + ((row * 1024 + oc * 4) ^ ((row & 3) << 4))) =
              pacc[mf][r] + bv;
        }
      }
    }
    __syncthreads();
    const int row = tid >> 5, colb = (tid & 31) * 8;
    const int t = win_tok_to_t(gw, hp * 32 + row);
    float* od = out + (size_t)t * 256 + colb;
#pragma unroll
    for (int i = 0; i < 2; ++i) {
      float4 rv = *(const float4*)((char*)sb.rep +
                    ((row * 1024 + (colb + i * 4) * 4) ^ ((row & 3) << 4)));
      ((float4*)od)[i] = make_float4(rv.x + xv[hp][i].x, rv.y + xv[hp][i].y,
                                     rv.z + xv[hp][i].z, rv.w + xv[hp][i].w);
    }
  }
}

// ---------------- fused MLP v8: 8 waves, single barrier/chunk (dbuf Hs) ----------------
__global__ __launch_bounds__(512)
void mlp_kernel(float* io, const u16* __restrict__ w1t, const u16* __restrict__ w2t,
                const float* __restrict__ fb1, const float* __restrict__ fb2,
                const float* __restrict__ g2, const float* __restrict__ bt2)
{
  __shared__ u16 Aln[16384];    // [64 tok][256 k] bf16, 16B-gran ^= tok&7  (32 KB)
  __shared__ u16 Hs[2][8192];   // dbuf [64 tok][128 h] bf16, gran ^= tok&7 (32 KB)
  const int tid = threadIdx.x, wid = tid >> 6, lane = tid & 63;
  const int l15 = lane & 15, g = lane >> 4;
  const int t0 = blockIdx.x * 64;

  // ---- stage Aln with fused LN2 (8 lanes per row, 32 cols each) ----
  {
    const int row = tid >> 3;          // 0..63
    const int cq = (tid & 7) * 32;
    const float* src = io + (size_t)(t0 + row) * 256 + cq;
    float vals[32];
    float s = 0.f, q = 0.f;
#pragma unroll
    for (int i = 0; i < 8; ++i) {
      float4 v = ((const float4*)src)[i];
      vals[i*4] = v.x; vals[i*4+1] = v.y; vals[i*4+2] = v.z; vals[i*4+3] = v.w;
      s += v.x + v.y + v.z + v.w;
      q += v.x*v.x + v.y*v.y + v.z*v.z + v.w*v.w;
    }
    s += __shfl_xor(s, 1, 64); q += __shfl_xor(q, 1, 64);
    s += __shfl_xor(s, 2, 64); q += __shfl_xor(q, 2, 64);
    s += __shfl_xor(s, 4, 64); q += __shfl_xor(q, 4, 64);
    float mean = s * 0.00390625f;
    float rstd = rsqrtf(q * 0.00390625f - mean * mean + 1e-5f);
#pragma unroll
    for (int i = 0; i < 4; ++i) {
      const int col = cq + i * 8;
      u16x8 o;
#pragma unroll
      for (int j = 0; j < 8; ++j)
        o[j] = f2bf((vals[i*8+j] - mean) * rstd * g2[col+j] + bt2[col+j]);
      const int gran = col >> 3;
      *(u16x8*)((char*)Aln + row * 512 + ((gran ^ (row & 7)) << 4)) = o;
    }
  }

  f32x4 acc2[4][2];   // [tf][of]: oc = wid*32 + of*16 + l15
#pragma unroll
  for (int m = 0; m < 4; ++m)
#pragma unroll
    for (int n = 0; n < 2; ++n) acc2[m][n] = (f32x4){0.f, 0.f, 0.f, 0.f};
  f32x4 acc1[4];

#define MGEMM1(c)                                                                 \
  {                                                                               \
    _Pragma("unroll")                                                             \
    for (int tf = 0; tf < 4; ++tf) acc1[tf] = (f32x4){0.f, 0.f, 0.f, 0.f};        \
    const u16* w1base = w1t + (size_t)((c) * 128 + wid * 16) * 256;               \
    _Pragma("unroll")                                                             \
    for (int ks = 0; ks < 8; ++ks) {                                              \
      bf16x8 af = *(const bf16x8*)(w1base + (size_t)l15 * 256 + ks * 32 + g * 8); \
      bf16x8 bfr[4];                                                              \
      _Pragma("unroll")                                                           \
      for (int tf = 0; tf < 4; ++tf) {                                            \
        const int tok = tf * 16 + l15;                                            \
        const int gran = ks * 4 + g;                                              \
        bfr[tf] = *(const bf16x8*)&Aln[tok * 256 + ((gran ^ (tok & 7)) << 3)];    \
      }                                                                           \
      _Pragma("unroll")                                                           \
      for (int tf = 0; tf < 4; ++tf)                                              \
        acc1[tf] = __builtin_amdgcn_mfma_f32_16x16x32_bf16(af, bfr[tf], acc1[tf], 0, 0, 0); \
    }                                                                             \
  }

#define MPACK(c)                                                                  \
  {                                                                               \
    char* hdst = (char*)Hs[(c) & 1];                                              \
    const int hcl = wid * 16 + g * 4;                                             \
    const float b0 = fb1[(c) * 128 + hcl];                                        \
    const float b1 = fb1[(c) * 128 + hcl + 1];                                    \
    const float b2v = fb1[(c) * 128 + hcl + 2];                                   \
    const float b3 = fb1[(c) * 128 + hcl + 3];                                    \
    _Pragma("unroll")                                                             \
    for (int tf = 0; tf < 4; ++tf) {                                              \
      const int tok = tf * 16 + l15;                                              \
      float p0 = gelu_f(acc1[tf][0] + b0);                                        \
      float p1 = gelu_f(acc1[tf][1] + b1);                                        \
      float p2 = gelu_f(acc1[tf][2] + b2v);                                       \
      float p3 = gelu_f(acc1[tf][3] + b3);                                        \
      unsigned int pa, pb;                                                        \
      asm("v_cvt_pk_bf16_f32 %0, %1, %2" : "=v"(pa) : "v"(p0), "v"(p1));          \
      asm("v_cvt_pk_bf16_f32 %0, %1, %2" : "=v"(pb) : "v"(p2), "v"(p3));          \
      uint2 w; w.x = pa; w.y = pb;                                                \
      *(uint2*)(hdst + tok * 256 + (((hcl >> 3) ^ (tok & 7)) << 4) + ((hcl & 4) << 1)) = w; \
    }                                                                             \
  }

#define MGEMM2(c)                                                                 \
  {                                                                               \
    const u16* hsrc = Hs[(c) & 1];                                                \
    const u16* w2base = w2t + (size_t)(wid * 32) * 1024 + (c) * 128;              \
    _Pragma("unroll")                                                             \
    for (int hk = 0; hk < 4; ++hk) {                                              \
      bf16x8 ah[4], bw[2];                                                        \
      _Pragma("unroll")                                                           \
      for (int tf = 0; tf < 4; ++tf) {                                            \
        const int tok = tf * 16 + l15;                                            \
        const int gran = hk * 4 + g;                                              \
        ah[tf] = *(const bf16x8*)&hsrc[tok * 128 + ((gran ^ (tok & 7)) << 3)];    \
      }                                                                           \
      _Pragma("unroll")                                                           \
      for (int of = 0; of < 2; ++of)                                              \
        bw[of] = *(const bf16x8*)(w2base + (size_t)(of * 16 + l15) * 1024 + hk * 32 + g * 8); \
      _Pragma("unroll")                                                           \
      for (int tf = 0; tf < 4; ++tf)                                              \
        _Pragma("unroll")                                                         \
        for (int of = 0; of < 2; ++of)                                            \
          acc2[tf][of] = __builtin_amdgcn_mfma_f32_16x16x32_bf16(ah[tf], bw[of], acc2[tf][of], 0, 0, 0); \
    }                                                                             \
  }

  __syncthreads();           // Aln visible
  MGEMM1(0);
  MPACK(0);
  __syncthreads();
#pragma unroll
  for (int c = 1; c < 8; ++c) {
    MGEMM2(c - 1);           // reads Hs[(c-1)&1]  (RAW fenced by prev barrier)
    MGEMM1(c);               // independent (Aln + w1)
    MPACK(c);                // writes Hs[c&1] (WAR vs GEMM2(c-2) fenced by prev barrier)
    __syncthreads();
  }
  MGEMM2(7);
#undef MGEMM1
#undef MPACK
#undef MGEMM2

  // ---- epilogue: + fc2 bias + residual (in-place) ----
#pragma unroll
  for (int tf = 0; tf < 4; ++tf) {
#pragma unroll
    for (int of = 0; of < 2; ++of) {
      const int oc = wid * 32 + of * 16 + l15;
      const float bv = fb2[oc];
#pragma unroll
      for (int r = 0; r < 4; ++r) {
        const size_t off = (size_t)(t0 + tf * 16 + g * 4 + r) * 256 + oc;
        io[off] = acc2[tf][of][r] + bv + io[off];
      }
    }
  }
}

// ---------------- launch ----------------
extern "C" void kernel_launch(void* const* d_in, const int* in_sizes, int n_in,
                              void* d_out, int out_size, void* d_ws, size_t ws_size,
                              hipStream_t stream)
{
  const float* x      = (const float*)d_in[0];
  const float* qkv_w  = (const float*)d_in[1];
  const float* qkv_b  = (const float*)d_in[2];
  const float* proj_w = (const float*)d_in[3];
  const float* proj_b = (const float*)d_in[4];
  const float* rpb    = (const float*)d_in[5];
  const float* g1     = (const float*)d_in[6];
  const float* b1     = (const float*)d_in[7];
  const float* g2     = (const float*)d_in[8];
  const float* b2     = (const float*)d_in[9];
  const float* fc1_w  = (const float*)d_in[10];
  const float* fc1_b  = (const float*)d_in[11];
  const float* fc2_w  = (const float*)d_in[12];
  const float* fc2_b  = (const float*)d_in[13];
  float* out = (float*)d_out;
  char* ws = (char*)d_ws;

  // bf16 transposed weights (1.5 MB)
  u16* qkvT  = (u16*)ws;            // [768][256]
  u16* projT = qkvT + 196608;       // [256][256]
  u16* fc1T  = projT + 65536;       // [1024][256]
  u16* fc2T  = fc1T + 262144;       // [256][1024]

  wconv_kernel<<<(196608 + 255) / 256, 256, 0, stream>>>(qkv_w, qkvT, 256, 768);
  wconv_kernel<<<(65536  + 255) / 256, 256, 0, stream>>>(proj_w, projT, 256, 256);
  wconv_kernel<<<(262144 + 255) / 256, 256, 0, stream>>>(fc1_w, fc1T, 256, 1024);
  wconv_kernel<<<(262144 + 255) / 256, 256, 0, stream>>>(fc2_w, fc2T, 1024, 256);

  fawp_kernel<<<NWIN_TOTAL, 1024, 0, stream>>>(x, g1, b1, qkvT, qkv_b, rpb,
                                               projT, proj_b, out);

  mlp_kernel<<<TOK_TOTAL / 64, 512, 0, stream>>>(out, fc1T, fc2T, fc1_b, fc2_b, g2, b2);
}